// Round 6
// baseline (560.210 us; speedup 1.0000x reference)
//
#include <hip/hip_runtime.h>
#include <cstdint>
#include <cstddef>

#define E_CNT 800000
#define N_CNT 50000
#define NT 6250  // tiles of 128 edges

typedef short bf16x8 __attribute__((ext_vector_type(8)));
typedef short s16x4 __attribute__((ext_vector_type(4)));
typedef float f32x4 __attribute__((ext_vector_type(4)));
typedef uint32_t u32x4 __attribute__((ext_vector_type(4)));

// ws byte offsets
#define OFF_CURSOR 0
#define OFF_WFN 200064
#define OFF_WFC 241024
#define OFF_W2F 281984
#define OFF_BIASN 298368
#define OFF_BIASC 298880
#define OFF_SRC 299520
#define OFF_DST 3499520
#define OFF_DIST 6699520
#define OFF_HB 8299520
#define REQ_FULL 14699520

#define NODE_BLKS 1024
#define COORD_BLKS 1024

__device__ __forceinline__ short f2bf(float v) {
  uint32_t u = __builtin_bit_cast(uint32_t, v);
  u = (u + 0x7FFFu + ((u >> 16) & 1u)) >> 16;
  return (short)u;
}
__device__ __forceinline__ float bf2f(short s) {
  uint32_t u = ((uint32_t)(uint16_t)s) << 16;
  return __builtin_bit_cast(float, u);
}
__device__ __forceinline__ uint32_t pack2(float lo, float hi) {
  return ((uint32_t)(uint16_t)f2bf(hi) << 16) | (uint32_t)(uint16_t)f2bf(lo);
}
__device__ __forceinline__ float silu_f(float v) {
  return v * (1.0f / (1.0f + __expf(-v)));
}

// ---- fused prep: init (copy+bf16 h) | fragment-linear weights | dst histogram
template <bool FULL>
__global__ void k_pre(const float* __restrict__ h, const float* __restrict__ x,
                      float* __restrict__ out, short* __restrict__ hb,
                      const int* __restrict__ eidx, int* __restrict__ cursor,
                      const float* __restrict__ W1n, const float* __restrict__ W1c,
                      const float* __restrict__ We2, const float* __restrict__ bn1,
                      const float* __restrict__ bc1, const float* __restrict__ be2,
                      const float* __restrict__ Wn2,
                      short* __restrict__ Wfn, short* __restrict__ Wfc,
                      short* __restrict__ W2f, float* __restrict__ biasn,
                      float* __restrict__ biasc) {
  const int b = (int)blockIdx.x;
  if (b < 3272) {
    const int i = b * 256 + (int)threadIdx.x;
    if (i < 800000) {
      const f32x4 v = ((const f32x4*)h)[i];
      ((f32x4*)out)[i] = v;
      if (FULL) {
        s16x4 p;
#pragma unroll
        for (int j = 0; j < 4; ++j) p[j] = f2bf(v[j]);
        *(s16x4*)(hb + i * 4) = p;
      }
    } else if (i < 837500) {
      ((f32x4*)out)[i] = ((const f32x4*)x)[i - 800000];
    }
  } else if (b < 3297) {
    const int idx = (b - 3272) * 4 + ((int)threadIdx.x >> 6);
    const int l = (int)threadIdx.x & 63;
    if (idx < 80) {
      const int fid = (idx < 40) ? idx : (idx - 40);
      const float* W1 = (idx < 40) ? W1n : W1c;
      short* Wf = (idx < 40) ? Wfn : Wfc;
      const int kt = fid >> 3, nt = fid & 7;
      const int row = nt * 16 + (l & 15);
      const int k0 = kt * 32 + (l >> 4) * 8;
      bf16x8 v;
#pragma unroll
      for (int j = 0; j < 8; ++j) {
        const int k = k0 + j;
        float val;
        if (k < 128) {
          val = W1[k * 128 + row];
        } else {
          float s = 0.f;
          for (int cc = 0; cc < 32; ++cc)
            s = fmaf(We2[(k - 128) * 32 + cc], W1[(128 + cc) * 128 + row], s);
          val = s;
        }
        v[j] = f2bf(val);
      }
      *(bf16x8*)&Wf[(fid * 64 + l) * 8] = v;
    } else if (idx < 96) {
      const int fid = idx - 80;
      const int kt2 = fid >> 2, nt2 = fid & 3;
      bf16x8 v;
#pragma unroll
      for (int j = 0; j < 8; ++j)
        v[j] = f2bf(Wn2[(kt2 * 32 + (l >> 4) * 8 + j) * 64 + nt2 * 16 + (l & 15)]);
      *(bf16x8*)&W2f[(fid * 64 + l) * 8] = v;
    } else if (idx == 96) {
      for (int col = l; col < 128; col += 64) {
        float sn = bn1[col], sc = bc1[col];
        for (int cc = 0; cc < 32; ++cc) {
          sn = fmaf(be2[cc], W1n[(128 + cc) * 128 + col], sn);
          sc = fmaf(be2[cc], W1c[(128 + cc) * 128 + col], sc);
        }
        biasn[col] = sn;
        biasc[col] = sc;
      }
    }
  } else if (FULL) {
    const int e = (b - 3297) * 256 + (int)threadIdx.x;
    if (e < E_CNT) atomicAdd(&cursor[eidx[E_CNT + e]], 1);
  }
}

__global__ __launch_bounds__(1024) void k_scan(int* __restrict__ cursor) {
  __shared__ int part[1024];
  const int t = (int)threadIdx.x;
  const int b0 = t * 49;
  int n = N_CNT - b0;
  n = n < 0 ? 0 : (n > 49 ? 49 : n);
  int s = 0;
  for (int i = 0; i < n; ++i) s += cursor[b0 + i];
  part[t] = s;
  __syncthreads();
  for (int off = 1; off < 1024; off <<= 1) {
    const int u = (t >= off) ? part[t - off] : 0;
    __syncthreads();
    part[t] += u;
    __syncthreads();
  }
  int run = (t == 0) ? 0 : part[t - 1];
  for (int i = 0; i < n; ++i) {
    const int old = cursor[b0 + i];
    cursor[b0 + i] = run;
    run += old;
  }
}

__global__ void k_fill(const int* __restrict__ eidx, const float* __restrict__ edist,
                       int* __restrict__ cursor, int* __restrict__ src_s,
                       int* __restrict__ dst_s, short* __restrict__ dist_s) {
  const int e = (int)(blockIdx.x * 256 + threadIdx.x);
  if (e < E_CNT) {
    const int d = eidx[E_CNT + e];
    const int pos = atomicAdd(&cursor[d], 1);
    src_s[pos] = eidx[e];
    dst_s[pos] = d;
    dist_s[pos] = f2bf(edist[e]);
  }
}

// ---- fused main: blocks [0,NODE_BLKS) = node path, rest = coord path ----
template <bool FULL>
__global__ __launch_bounds__(256, 2) void k_main(
    const float* __restrict__ h, const short* __restrict__ hb,
    const float* __restrict__ x, const float* __restrict__ edist,
    const float* __restrict__ We1, const float* __restrict__ be1,
    const float* __restrict__ bn2, const float* __restrict__ Wc2,
    const int* __restrict__ eidx,
    const int* __restrict__ src_s, const int* __restrict__ dst_s,
    const short* __restrict__ dist_s,
    const short* __restrict__ Wfn, const short* __restrict__ Wfc,
    const short* __restrict__ W2f,
    const float* __restrict__ biasn, const float* __restrict__ biasc,
    float* __restrict__ out, float* __restrict__ xo) {
  __shared__ __align__(16) short scr[4][16 * 136];

  const int tid = (int)threadIdx.x;
  const int w = tid >> 6, l = tid & 63, g = l >> 4, c = l & 15;
  const f32x4 vzero = {0.f, 0.f, 0.f, 0.f};

  float we1s[8], be1s[8];
#pragma unroll
  for (int j = 0; j < 8; ++j) { we1s[j] = We1[g * 8 + j]; be1s[j] = be1[g * 8 + j]; }

  if ((int)blockIdx.x < NODE_BLKS) {
    // ================= node path =================
    const int bid = (int)blockIdx.x;
    short* myscr = &scr[w][0];
    float bias1[8];
#pragma unroll
    for (int nt = 0; nt < 8; ++nt) bias1[nt] = biasn[nt * 16 + c];
    float bias2[4];
#pragma unroll
    for (int nt = 0; nt < 4; ++nt) bias2[nt] = bn2[nt * 16 + c];

    for (int t = bid; t < NT; t += NODE_BLKS) {
      const short* wft = Wfn;
      const short* w2t = W2f;
      asm volatile("" : "+v"(wft), "+v"(w2t));

      const int base = t * 128 + w * 32;
      const int e0 = base + 2 * c, e1 = e0 + 1;
      int s0, s1, d0, d1;
      float dd0, dd1;
      if (FULL) {
        s0 = src_s[e0]; s1 = src_s[e1];
        d0 = dst_s[e0]; d1 = dst_s[e1];
        dd0 = bf2f(dist_s[e0]); dd1 = bf2f(dist_s[e1]);
      } else {
        s0 = eidx[e0]; s1 = eidx[e1];
        d0 = eidx[E_CNT + e0]; d1 = eidx[E_CNT + e1];
        dd0 = edist[e0]; dd1 = edist[e1];
      }

      f32x4 acc[2][8];
#pragma unroll
      for (int mt = 0; mt < 2; ++mt)
#pragma unroll
        for (int nt = 0; nt < 8; ++nt) acc[mt][nt] = vzero;

#pragma unroll
      for (int kt = 0; kt < 5; ++kt) {
        bf16x8 a0, a1;
        if (kt < 4) {
          const size_t r0 = (size_t)((kt < 2) ? s0 : d0) * 64 + (kt & 1) * 32 + g * 8;
          const size_t r1 = (size_t)((kt < 2) ? s1 : d1) * 64 + (kt & 1) * 32 + g * 8;
          if (FULL) {
            a0 = *(const bf16x8*)&hb[r0];
            a1 = *(const bf16x8*)&hb[r1];
          } else {
            const f32x4 pa = *(const f32x4*)(h + r0), pb = *(const f32x4*)(h + r0 + 4);
            const f32x4 qa = *(const f32x4*)(h + r1), qb = *(const f32x4*)(h + r1 + 4);
            u32x4 u0 = {pack2(pa[0], pa[1]), pack2(pa[2], pa[3]),
                        pack2(pb[0], pb[1]), pack2(pb[2], pb[3])};
            u32x4 u1 = {pack2(qa[0], qa[1]), pack2(qa[2], qa[3]),
                        pack2(qb[0], qb[1]), pack2(qb[2], qb[3])};
            a0 = __builtin_bit_cast(bf16x8, u0);
            a1 = __builtin_bit_cast(bf16x8, u1);
          }
        } else {
#pragma unroll
          for (int j = 0; j < 8; ++j) {
            a0[j] = f2bf(silu_f(fmaf(dd0, we1s[j], be1s[j])));
            a1[j] = f2bf(silu_f(fmaf(dd1, we1s[j], be1s[j])));
          }
        }
#pragma unroll
        for (int nt = 0; nt < 8; ++nt) {
          const bf16x8 b = *(const bf16x8*)&wft[(((kt << 3) + nt) << 9) + (l << 3)];
          acc[0][nt] = __builtin_amdgcn_mfma_f32_16x16x32_bf16(a0, b, acc[0][nt], 0, 0, 0);
          acc[1][nt] = __builtin_amdgcn_mfma_f32_16x16x32_bf16(a1, b, acc[1][nt], 0, 0, 0);
        }
      }

      // per-mt: silu->scr, GEMM2, RLE atomics (acc2 reused -> 32 fewer regs)
#pragma unroll
      for (int mt = 0; mt < 2; ++mt) {
#pragma unroll
        for (int nt = 0; nt < 8; ++nt)
#pragma unroll
          for (int r = 0; r < 4; ++r)
            myscr[(g * 4 + r) * 136 + nt * 16 + c] = f2bf(silu_f(acc[mt][nt][r] + bias1[nt]));

        f32x4 acc2[4];
#pragma unroll
        for (int nt2 = 0; nt2 < 4; ++nt2) acc2[nt2] = vzero;
#pragma unroll
        for (int kt2 = 0; kt2 < 4; ++kt2) {
          const bf16x8 a2 = *(const bf16x8*)&myscr[c * 136 + kt2 * 32 + g * 8];
#pragma unroll
          for (int nt2 = 0; nt2 < 4; ++nt2) {
            const bf16x8 b2 = *(const bf16x8*)&w2t[(((kt2 << 2) + nt2) << 9) + (l << 3)];
            acc2[nt2] = __builtin_amdgcn_mfma_f32_16x16x32_bf16(a2, b2, acc2[nt2], 0, 0, 0);
          }
        }

        const int dmt = mt ? d1 : d0;
        int des[4];
#pragma unroll
        for (int r = 0; r < 4; ++r) des[r] = __shfl(dmt, 4 * g + r);

        float run[4];
        int cur = des[0];
#pragma unroll
        for (int nt2 = 0; nt2 < 4; ++nt2) run[nt2] = acc2[nt2][0] + bias2[nt2];
#pragma unroll
        for (int s = 1; s < 4; ++s) {
          if (des[s] == cur) {
#pragma unroll
            for (int nt2 = 0; nt2 < 4; ++nt2) run[nt2] += acc2[nt2][s] + bias2[nt2];
          } else {
#pragma unroll
            for (int nt2 = 0; nt2 < 4; ++nt2)
              unsafeAtomicAdd(&out[(size_t)cur * 64 + nt2 * 16 + c], run[nt2]);
            cur = des[s];
#pragma unroll
            for (int nt2 = 0; nt2 < 4; ++nt2) run[nt2] = acc2[nt2][s] + bias2[nt2];
          }
        }
#pragma unroll
        for (int nt2 = 0; nt2 < 4; ++nt2)
          unsafeAtomicAdd(&out[(size_t)cur * 64 + nt2 * 16 + c], run[nt2]);
      }
    }
  } else {
    // ================= coord path =================
    const int bid = (int)blockIdx.x - NODE_BLKS;
    float bias1[8], wc2l[8];
#pragma unroll
    for (int nt = 0; nt < 8; ++nt) {
      bias1[nt] = biasc[nt * 16 + c];
      wc2l[nt] = Wc2[nt * 16 + c];
    }

    for (int t = bid; t < NT; t += COORD_BLKS) {
      const short* wft = Wfc;
      asm volatile("" : "+v"(wft));

      const int base = t * 128 + w * 32;
      const int e0 = base + c, e1 = e0 + 16;
      const int s0 = eidx[e0], s1 = eidx[e1];
      const int d0 = eidx[E_CNT + e0], d1 = eidx[E_CNT + e1];
      const float dd0 = edist[e0], dd1 = edist[e1];

      f32x4 acc[2][8];
#pragma unroll
      for (int mt = 0; mt < 2; ++mt)
#pragma unroll
        for (int nt = 0; nt < 8; ++nt) acc[mt][nt] = vzero;

#pragma unroll
      for (int kt = 0; kt < 5; ++kt) {
        bf16x8 a0, a1;
        if (kt < 4) {
          const size_t r0 = (size_t)((kt < 2) ? s0 : d0) * 64 + (kt & 1) * 32 + g * 8;
          const size_t r1 = (size_t)((kt < 2) ? s1 : d1) * 64 + (kt & 1) * 32 + g * 8;
          if (FULL) {
            a0 = *(const bf16x8*)&hb[r0];
            a1 = *(const bf16x8*)&hb[r1];
          } else {
            const f32x4 pa = *(const f32x4*)(h + r0), pb = *(const f32x4*)(h + r0 + 4);
            const f32x4 qa = *(const f32x4*)(h + r1), qb = *(const f32x4*)(h + r1 + 4);
            u32x4 u0 = {pack2(pa[0], pa[1]), pack2(pa[2], pa[3]),
                        pack2(pb[0], pb[1]), pack2(pb[2], pb[3])};
            u32x4 u1 = {pack2(qa[0], qa[1]), pack2(qa[2], qa[3]),
                        pack2(qb[0], qb[1]), pack2(qb[2], qb[3])};
            a0 = __builtin_bit_cast(bf16x8, u0);
            a1 = __builtin_bit_cast(bf16x8, u1);
          }
        } else {
#pragma unroll
          for (int j = 0; j < 8; ++j) {
            a0[j] = f2bf(silu_f(fmaf(dd0, we1s[j], be1s[j])));
            a1[j] = f2bf(silu_f(fmaf(dd1, we1s[j], be1s[j])));
          }
        }
#pragma unroll
        for (int nt = 0; nt < 8; ++nt) {
          const bf16x8 b = *(const bf16x8*)&wft[(((kt << 3) + nt) << 9) + (l << 3)];
          acc[0][nt] = __builtin_amdgcn_mfma_f32_16x16x32_bf16(a0, b, acc[0][nt], 0, 0, 0);
          acc[1][nt] = __builtin_amdgcn_mfma_f32_16x16x32_bf16(a1, b, acc[1][nt], 0, 0, 0);
        }
      }

#pragma unroll
      for (int mt = 0; mt < 2; ++mt) {
        float p[4] = {0.f, 0.f, 0.f, 0.f};
#pragma unroll
        for (int nt = 0; nt < 8; ++nt)
#pragma unroll
          for (int r = 0; r < 4; ++r)
            p[r] += silu_f(acc[mt][nt][r] + bias1[nt]) * wc2l[nt];
#pragma unroll
        for (int m = 1; m < 16; m <<= 1)
#pragma unroll
          for (int r = 0; r < 4; ++r) p[r] += __shfl_xor(p[r], m);

        const int srcm = mt ? s1 : s0;
        const int dstm = mt ? d1 : d0;
        const int el = (g * 4 + c) & 15;
        const int se = __shfl(srcm, el);
        const int de = __shfl(dstm, el);
        const float cw = (c == 0) ? p[0] : (c == 1) ? p[1] : (c == 2) ? p[2] : p[3];
        if (c < 4) {
          const float ax = x[se * 3 + 0] - x[de * 3 + 0];
          const float ay = x[se * 3 + 1] - x[de * 3 + 1];
          const float az = x[se * 3 + 2] - x[de * 3 + 2];
          float len = sqrtf(fmaf(ax, ax, fmaf(ay, ay, az * az)));
          len = fmaxf(len, 1e-8f);
          const float scl = cw / len;
          unsafeAtomicAdd(&xo[de * 3 + 0], scl * ax);
          unsafeAtomicAdd(&xo[de * 3 + 1], scl * ay);
          unsafeAtomicAdd(&xo[de * 3 + 2], scl * az);
        }
      }
    }
  }
}

extern "C" void kernel_launch(void* const* d_in, const int* in_sizes, int n_in,
                              void* d_out, int out_size, void* d_ws, size_t ws_size,
                              hipStream_t stream) {
  const float* h = (const float*)d_in[0];
  const float* x = (const float*)d_in[1];
  const float* edist = (const float*)d_in[2];
  const float* We1 = (const float*)d_in[3];
  const float* be1 = (const float*)d_in[4];
  const float* We2 = (const float*)d_in[5];
  const float* be2 = (const float*)d_in[6];
  const float* Wn1 = (const float*)d_in[7];
  const float* bn1 = (const float*)d_in[8];
  const float* Wn2 = (const float*)d_in[9];
  const float* bn2 = (const float*)d_in[10];
  const float* Wc1 = (const float*)d_in[11];
  const float* bc1 = (const float*)d_in[12];
  const float* Wc2 = (const float*)d_in[13];
  const int* eidx = (const int*)d_in[14];
  float* out = (float*)d_out;
  float* xo = out + 3200000;

  char* wsb = (char*)d_ws;
  int* cursor = (int*)(wsb + OFF_CURSOR);
  short* Wfn = (short*)(wsb + OFF_WFN);
  short* Wfc = (short*)(wsb + OFF_WFC);
  short* W2f = (short*)(wsb + OFF_W2F);
  float* biasn = (float*)(wsb + OFF_BIASN);
  float* biasc = (float*)(wsb + OFF_BIASC);
  int* src_s = (int*)(wsb + OFF_SRC);
  int* dst_s = (int*)(wsb + OFF_DST);
  short* dist_s = (short*)(wsb + OFF_DIST);
  short* hb = (short*)(wsb + OFF_HB);

  const bool full = (ws_size >= (size_t)REQ_FULL);

  if (full) {
    hipMemsetAsync(cursor, 0, N_CNT * sizeof(int), stream);
    k_pre<true><<<dim3(6422), dim3(256), 0, stream>>>(h, x, out, hb, eidx, cursor,
                                                      Wn1, Wc1, We2, bn1, bc1, be2, Wn2,
                                                      Wfn, Wfc, W2f, biasn, biasc);
    k_scan<<<dim3(1), dim3(1024), 0, stream>>>(cursor);
    k_fill<<<dim3(3125), dim3(256), 0, stream>>>(eidx, edist, cursor, src_s, dst_s, dist_s);
    k_main<true><<<dim3(NODE_BLKS + COORD_BLKS), dim3(256), 0, stream>>>(
        h, hb, x, edist, We1, be1, bn2, Wc2, eidx, src_s, dst_s, dist_s,
        Wfn, Wfc, W2f, biasn, biasc, out, xo);
  } else {
    k_pre<false><<<dim3(3297), dim3(256), 0, stream>>>(h, x, out, nullptr, eidx, nullptr,
                                                       Wn1, Wc1, We2, bn1, bc1, be2, Wn2,
                                                       Wfn, Wfc, W2f, biasn, biasc);
    k_main<false><<<dim3(NODE_BLKS + COORD_BLKS), dim3(256), 0, stream>>>(
        h, nullptr, x, edist, We1, be1, bn2, Wc2, eidx, nullptr, nullptr, nullptr,
        Wfn, Wfc, W2f, biasn, biasc, out, xo);
  }
}